// Round 1
// baseline (5079.994 us; speedup 1.0000x reference)
//
#include <hip/hip_runtime.h>
#include <math.h>

// Problem constants (fixed by reference file)
#define NB   512    // N = batch of user pairs
#define MM   254    // M uav nodes
#define SS   256    // S = M + 2 graph nodes per b
#define HH   128    // H hidden
#define RTOT 1278   // 2N + M rows in `outputs`

__device__ __forceinline__ float sigm(float x)   { return 1.0f / (1.0f + __expf(-x)); }
__device__ __forceinline__ float tanh_f(float x) { return 1.0f - 2.0f / (1.0f + __expf(2.0f * x)); }

// Precompute, per node row r: e = pos @ W_embed + b_embed (128),
//   W1eT[h][r] = (e @ att_W1)[h]   (transposed for coalesced decode reads)
//   EWi[r][j]  = (e @ lstm_Wi)[j]  (j in [0,512))
__global__ __launch_bounds__(128) void precompute_k(
    const float* __restrict__ outputs, const float* __restrict__ Wemb,
    const float* __restrict__ bemb, const float* __restrict__ Wi,
    const float* __restrict__ W1, float* __restrict__ EWi, float* __restrict__ W1eT)
{
  int r = blockIdx.x;
  int t = threadIdx.x;  // 128
  __shared__ float e[HH];
  float px = outputs[2 * r], py = outputs[2 * r + 1];
  e[t] = px * Wemb[t] + py * Wemb[HH + t] + bemb[t];
  __syncthreads();
  float acc = 0.f;
#pragma unroll 8
  for (int h = 0; h < HH; ++h) acc = fmaf(e[h], W1[h * HH + t], acc);
  W1eT[t * RTOT + r] = acc;
#pragma unroll
  for (int c4 = 0; c4 < 4; ++c4) {
    int j = t + c4 * HH;
    float a = 0.f;
#pragma unroll 8
    for (int h = 0; h < HH; ++h) a = fmaf(e[h], Wi[h * 512 + j], a);
    EWi[(size_t)r * 512 + j] = a;
  }
}

// One block per batch element b. 256 threads. 256 sequential steps.
__global__ __launch_bounds__(256) void decode_k(
    const float* __restrict__ outputs, const float* __restrict__ Wh,
    const float* __restrict__ lb, const float* __restrict__ W2,
    const float* __restrict__ av, const float* __restrict__ EWi,
    const float* __restrict__ W1eT, float* __restrict__ maxd_out)
{
  int b = blockIdx.x;
  int t = threadIdx.x;  // 256
  __shared__ float hS[HH], cS[HH], qS[HH], gS[4 * HH], maskS[SS], vS[HH];
  __shared__ float rv[SS];
  __shared__ int ri[SS];
  __shared__ int curS;
  __shared__ float pxS, pyS, mdS;

  if (t < HH) { hS[t] = 0.f; cS[t] = 0.f; vS[t] = av[t]; }
  maskS[t] = (t == 0) ? -INFINITY : 0.f;
  if (t == 0) {
    curS = b; mdS = 0.f;
    pxS = outputs[2 * b]; pyS = outputs[2 * b + 1];
  }
  __syncthreads();

  for (int k = 0; k < SS; ++k) {
    if (t == 0) maskS[SS - 1] = (k == 0) ? -INFINITY : 0.f;
    __syncthreads();
    int cur = curS;

    // gates[j] = EWi[cur][j] + lstm_b[j] + sum_k h[k]*Wh[k][j] ; j = 2t, 2t+1
    {
      const float* ew = EWi + (size_t)cur * 512;
      float a0 = ew[2 * t] + lb[2 * t];
      float a1 = ew[2 * t + 1] + lb[2 * t + 1];
#pragma unroll 8
      for (int kk = 0; kk < HH; ++kk) {
        float hv = hS[kk];
        float2 w = *(const float2*)(Wh + (size_t)kk * 512 + 2 * t);
        a0 = fmaf(hv, w.x, a0);
        a1 = fmaf(hv, w.y, a1);
      }
      gS[2 * t] = a0; gS[2 * t + 1] = a1;
    }
    __syncthreads();

    // LSTM cell update (order: i, f, g, o)
    if (t < HH) {
      float iv = sigm(gS[t]);
      float fv = sigm(gS[HH + t]);
      float gv = tanh_f(gS[2 * HH + t]);
      float ov = sigm(gS[3 * HH + t]);
      float cn = fv * cS[t] + iv * gv;
      cS[t] = cn;
      hS[t] = ov * tanh_f(cn);
    }
    __syncthreads();

    // q[j] = sum_k h[k] * W2[k][j]
    if (t < HH) {
      float a = 0.f;
#pragma unroll 8
      for (int kk = 0; kk < HH; ++kk) a = fmaf(hS[kk], W2[kk * HH + t], a);
      qS[t] = a;
    }
    __syncthreads();

    // logits[s] = sum_h v[h]*tanh(W1e[r(s)][h] + q[h]) + mask[s] ; s = t
    {
      int r = (t == 0) ? b : (t <= MM ? 2 * NB + (t - 1) : NB + b);
      float acc = 0.f;
#pragma unroll 4
      for (int hh = 0; hh < HH; ++hh) {
        float w = W1eT[hh * RTOT + r];
        acc = fmaf(vS[hh], tanh_f(w + qS[hh]), acc);
      }
      rv[t] = acc + maskS[t];
      ri[t] = t;
    }
    __syncthreads();

    // argmax with first-index tie-break (matches jnp.argmax)
    for (int off = 128; off > 0; off >>= 1) {
      if (t < off) {
        float v2 = rv[t + off]; int i2 = ri[t + off];
        float v1 = rv[t];       int i1 = ri[t];
        if (v2 > v1 || (v2 == v1 && i2 < i1)) { rv[t] = v2; ri[t] = i2; }
      }
      __syncthreads();
    }

    if (t == 0) {
      int idx = ri[0];
      int rn = (idx == 0) ? b : (idx <= MM ? 2 * NB + (idx - 1) : NB + b);
      float nx = outputs[2 * rn], ny = outputs[2 * rn + 1];
      float dx = nx - pxS, dy = ny - pyS;
      float d = sqrtf(dx * dx + dy * dy + 1e-12f);
      if (d > mdS) mdS = d;
      maskS[idx] = maskS[idx] + (-INFINITY);
      curS = rn; pxS = nx; pyS = ny;
    }
    __syncthreads();
  }
  if (t == 0) maxd_out[b] = mdS;
}

__global__ __launch_bounds__(512) void reduce_k(const float* __restrict__ maxd,
                                               float* __restrict__ out)
{
  __shared__ float s[512];
  int t = threadIdx.x;
  s[t] = maxd[t];
  __syncthreads();
  for (int off = 256; off > 0; off >>= 1) {
    if (t < off) s[t] += s[t + off];
    __syncthreads();
  }
  if (t == 0) out[0] = s[0] * (1.0f / 512.0f);
}

extern "C" void kernel_launch(void* const* d_in, const int* in_sizes, int n_in,
                              void* d_out, int out_size, void* d_ws, size_t ws_size,
                              hipStream_t stream) {
  const float* outputs = (const float*)d_in[0];
  const float* Wemb    = (const float*)d_in[1];
  const float* bemb    = (const float*)d_in[2];
  const float* Wi      = (const float*)d_in[3];
  const float* Wh      = (const float*)d_in[4];
  const float* lb      = (const float*)d_in[5];
  const float* W1      = (const float*)d_in[6];
  const float* W2      = (const float*)d_in[7];
  const float* av      = (const float*)d_in[8];
  // d_in[9] = N (known constant 512)

  float* ws   = (float*)d_ws;
  float* EWi  = ws;                          // 1278 * 512 floats
  float* W1eT = EWi + (size_t)RTOT * 512;    // 128 * 1278 floats
  float* maxd = W1eT + (size_t)HH * RTOT;    // 512 floats

  hipLaunchKernelGGL(precompute_k, dim3(RTOT), dim3(HH), 0, stream,
                     outputs, Wemb, bemb, Wi, W1, EWi, W1eT);
  hipLaunchKernelGGL(decode_k, dim3(NB), dim3(256), 0, stream,
                     outputs, Wh, lb, W2, av, EWi, W1eT, maxd);
  hipLaunchKernelGGL(reduce_k, dim3(1), dim3(512), 0, stream, maxd, (float*)d_out);
}